// Round 2
// baseline (1288.934 us; speedup 1.0000x reference)
//
#include <hip/hip_runtime.h>
#include <cstdint>

// ---- problem constants ----
constexpr int B_       = 8;
constexpr int NPG_     = 12500;    // nodes per graph
constexpr int KSEL_    = 64;       // sort-pool k
constexpr int TOTAL_N_ = 100000;
constexpr int TOTAL_E_ = 1600000;
constexpr int NKEY_    = 16384;    // padded per-graph key count (pow2 >= NPG_)
constexpr int NB_SCAN  = (TOTAL_N_ + 255) / 256;   // 391
constexpr int OUT_ROW  = KSEL_ * (128 + 32);       // 10240
constexpr int NBLK_    = 2048;     // blocks for node-parallel kernels (8 XCD chunks of 256)
constexpr int CHUNK_   = 13;       // nodes per wave: 1024 waves/graph * 13 >= 12500

__device__ __forceinline__ float lrelu(float v){ return v >= 0.f ? v : 0.01f * v; }
__device__ __forceinline__ int   rlanei(int x, int l){ return __builtin_amdgcn_readlane(x, l); }
__device__ __forceinline__ float rlanef(float x, int l){
  return __uint_as_float(__builtin_amdgcn_readlane((int)__float_as_uint(x), l));
}
__device__ __forceinline__ int imin(int a, int b){ return a < b ? a : b; }

// ---------------- degrees ----------------
__global__ void deg_kernel(const int* __restrict__ src, const int* __restrict__ dst,
                           int* __restrict__ out_cnt, int* __restrict__ in_cnt){
  int i = blockIdx.x * 256 + threadIdx.x;
  if (i < TOTAL_E_){
    atomicAdd(&out_cnt[src[i]], 1);
    atomicAdd(&in_cnt[dst[i]], 1);
  }
}

__global__ void rsq_kernel(const int* __restrict__ in_cnt, const int* __restrict__ out_cnt,
                           float* __restrict__ rsq_in, float* __restrict__ rsq_out){
  int i = blockIdx.x * 256 + threadIdx.x;
  if (i < TOTAL_N_){
    int ic = in_cnt[i];  if (ic < 1) ic = 1;
    int oc = out_cnt[i]; if (oc < 1) oc = 1;
    rsq_in[i]  = rsqrtf((float)ic);
    rsq_out[i] = rsqrtf((float)oc);
  }
}

// ---------------- exclusive scan (3 kernels) ----------------
__global__ void scan_blocks(const int* __restrict__ cnt, int* __restrict__ off, int* __restrict__ bsum){
  __shared__ int tmp[256];
  int t = threadIdx.x;
  int i = blockIdx.x * 256 + t;
  int x = (i < TOTAL_N_) ? cnt[i] : 0;
  tmp[t] = x;
  __syncthreads();
  for (int d = 1; d < 256; d <<= 1){
    int v = (t >= d) ? tmp[t - d] : 0;
    __syncthreads();
    tmp[t] += v;
    __syncthreads();
  }
  if (i < TOTAL_N_) off[i] = tmp[t] - x;
  if (t == 255) bsum[blockIdx.x] = tmp[255];
}

__global__ void scan_sums(int* __restrict__ bsum, int nb){
  __shared__ int tmp[512];
  int t = threadIdx.x;
  int x = (t < nb) ? bsum[t] : 0;
  tmp[t] = x;
  __syncthreads();
  for (int d = 1; d < 512; d <<= 1){
    int v = (t >= d) ? tmp[t - d] : 0;
    __syncthreads();
    tmp[t] += v;
    __syncthreads();
  }
  if (t < nb) bsum[t] = tmp[t] - x;
}

__global__ void scan_add(int* __restrict__ off, const int* __restrict__ bsum){
  int i = blockIdx.x * 256 + threadIdx.x;
  if (i < TOTAL_N_) off[i] += bsum[blockIdx.x];
}

// ---------------- CSR fill (bucket by dst) ----------------
// csr_w = raw edge weight (layer 2), csr_wr = ew * rsq_out[src] (layer 1)
__global__ void fill_csr(const int* __restrict__ src, const int* __restrict__ dst,
                         const float* __restrict__ ew, const float* __restrict__ rsq_out,
                         const int* __restrict__ off, int* __restrict__ cursor,
                         int* __restrict__ csr_src, float* __restrict__ csr_w,
                         float* __restrict__ csr_wr){
  int i = blockIdx.x * 256 + threadIdx.x;
  if (i < TOTAL_E_){
    int s = src[i];
    int d = dst[i];
    float w = ew[i];
    int p = atomicAdd(&cursor[d], 1);
    int slot = off[d] + p;
    csr_src[slot] = s;
    csr_w[slot]   = w;
    csr_wr[slot]  = w * rsq_out[s];
  }
}

// ---------------- layer 1: fused SpMM (64-d) + W1 projection ----------------
// h1_raw[v][c] = rsq_in[v] * sum_k ( sum_e csr_wr * feat[src][k] ) * W1[k][c]
__global__ void spmm1_fused(const int* __restrict__ off, const int* __restrict__ cnt,
                            const int* __restrict__ csr_src, const float* __restrict__ csr_wr,
                            const float* __restrict__ feat, const float* __restrict__ W1,
                            const float* __restrict__ rsq_in, float* __restrict__ h1){
  __shared__ float w[64 * 128];   // 32 KB, loaded once per block
  int t = threadIdx.x;
  for (int i = t; i < 64 * 128; i += 256) w[i] = W1[i];
  __syncthreads();

  int g    = blockIdx.x & 7;                       // graph == XCD chunk
  int r    = (blockIdx.x >> 3) * 4 + (t >> 6);     // 0..1023 wave slot within graph
  int lane = t & 63;
  int v0   = g * NPG_ + r * CHUNK_;
  int vend = imin(v0 + CHUNK_, (g + 1) * NPG_);

  for (int v = v0; v < vend; ++v){
    int s0 = __builtin_amdgcn_readfirstlane(off[v]);
    int n  = __builtin_amdgcn_readfirstlane(cnt[v]);
    float acc = 0.f;
    for (int e0 = 0; e0 < n; e0 += 64){
      int batch = n - e0; if (batch > 64) batch = 64;
      int ms = 0; float mw = 0.f;
      if (lane < batch){
        ms = csr_src[s0 + e0 + lane];
        mw = csr_wr[s0 + e0 + lane];
      }
      int j = 0;
      for (; j + 4 <= batch; j += 4){
        int sA = rlanei(ms, j),   sB = rlanei(ms, j+1);
        int sC = rlanei(ms, j+2), sD = rlanei(ms, j+3);
        float wA = rlanef(mw, j),   wB = rlanef(mw, j+1);
        float wC = rlanef(mw, j+2), wD = rlanef(mw, j+3);
        float fA = feat[(size_t)sA * 64 + lane];
        float fB = feat[(size_t)sB * 64 + lane];
        float fC = feat[(size_t)sC * 64 + lane];
        float fD = feat[(size_t)sD * 64 + lane];
        acc = fmaf(wA, fA, acc); acc = fmaf(wB, fB, acc);
        acc = fmaf(wC, fC, acc); acc = fmaf(wD, fD, acc);
      }
      for (; j < batch; ++j){
        int sA = rlanei(ms, j); float wA = rlanef(mw, j);
        acc = fmaf(wA, feat[(size_t)sA * 64 + lane], acc);
      }
    }
    // epilogue: project 64 -> 128 (lane owns columns lane and lane+64)
    float a0 = 0.f, a1 = 0.f;
    #pragma unroll
    for (int k = 0; k < 64; ++k){
      float ak = rlanef(acc, k);
      a0 = fmaf(ak, w[k * 128 + lane], a0);
      a1 = fmaf(ak, w[k * 128 + 64 + lane], a1);
    }
    float ri = rsq_in[v];
    h1[(size_t)v * 128 + lane]      = a0 * ri;
    h1[(size_t)v * 128 + 64 + lane] = a1 * ri;
  }
}

// per-(graph,channel) sum & sumsq over RAW h1, D=128
__global__ void stats1(const float* __restrict__ h, float* __restrict__ gsum, float* __restrict__ gsq){
  int b = blockIdx.x / 25, chunk = blockIdx.x % 25;
  int t = threadIdx.x;
  int c = t & 127, r0 = t >> 7;
  size_t base = ((size_t)b * NPG_ + (size_t)chunk * 500) * 128;
  float s = 0.f, q = 0.f;
  for (int r = r0; r < 500; r += 2){
    float v = h[base + (size_t)r * 128 + c];
    s += v; q += v * v;
  }
  __shared__ float ls[256], lq[256];
  ls[t] = s; lq[t] = q;
  __syncthreads();
  if (t < 128){
    s = ls[t] + ls[t + 128];
    q = lq[t] + lq[t + 128];
    atomicAdd(&gsum[b * 128 + c], s);
    atomicAdd(&gsq [b * 128 + c], q);
  }
}

__global__ void finalize1(const float* __restrict__ gsum, const float* __restrict__ gsq,
                          const float* __restrict__ gamma, const float* __restrict__ beta,
                          const float* __restrict__ alpha, float* __restrict__ mul, float* __restrict__ add){
  int i = threadIdx.x;            // 1024 = 8*128
  int c = i & 127;
  const float invn = 1.0f / (float)NPG_;
  float m = gsum[i] * invn;
  float a = alpha[c];
  float var = gsq[i] * invn - 2.f * a * m * m + a * a * m * m;
  float mu = gamma[c] * rsqrtf(var + 1e-5f);
  mul[i] = mu;
  add[i] = beta[c] - mu * a * m;
}

// ---------------- fused: normalize h1 (in regs) + sort keys + project to h2p ----------------
// h1 stays RAW in memory. h2p[v][c] = rsq_out[v] * sum_k lrelu(norm(h1))[k] * W2[k][c]
__global__ void normproj(const float* __restrict__ h1,
                         const float* __restrict__ mul, const float* __restrict__ add,
                         const float* __restrict__ rsq_out, const float* __restrict__ W2,
                         unsigned long long* __restrict__ keys, float* __restrict__ h2p){
  __shared__ float w2[128 * 32];  // 16 KB
  int t = threadIdx.x;
  for (int i = t; i < 128 * 32; i += 256) w2[i] = W2[i];
  __syncthreads();

  int g    = blockIdx.x & 7;
  int r    = (blockIdx.x >> 3) * 4 + (t >> 6);
  int lane = t & 63;
  int c    = lane & 31, hh = lane >> 5;
  int wbase = hh * 64 * 32 + c;   // W2 row block base for this lane's k-half

  float m0 = mul[g * 128 + lane],      aA0 = add[g * 128 + lane];
  float m1 = mul[g * 128 + 64 + lane], aA1 = add[g * 128 + 64 + lane];

  int v0   = g * NPG_ + r * CHUNK_;
  int vend = imin(v0 + CHUNK_, (g + 1) * NPG_);

  for (int v = v0; v < vend; ++v){
    float x0 = h1[(size_t)v * 128 + lane];
    float x1 = h1[(size_t)v * 128 + 64 + lane];
    x0 = lrelu(fmaf(m0, x0, aA0));
    x1 = lrelu(fmaf(m1, x1, aA1));
    // sort key: max channel (descending value, ascending index tie-break)
    float mx = fmaxf(x0, x1);
    for (int o = 1; o < 64; o <<= 1) mx = fmaxf(mx, __shfl_xor(mx, o));
    if (lane == 0){
      unsigned u = __float_as_uint(mx);
      u ^= (u >> 31) ? 0xFFFFFFFFu : 0x80000000u;
      int nloc = v - g * NPG_;
      keys[(size_t)g * NKEY_ + nloc] = ((unsigned long long)(~u) << 32) | (unsigned)nloc;
    }
    // project 128 -> 32: lanes 0..31 do k=0..63, lanes 32..63 do k=64..127
    float acc = 0.f;
    #pragma unroll
    for (int kk = 0; kk < 64; ++kk){
      float sa = rlanef(x0, kk);
      float sb = rlanef(x1, kk);
      float vk = hh ? sb : sa;
      acc = fmaf(vk, w2[wbase + kk * 32], acc);
    }
    acc += __shfl_xor(acc, 32);
    if (hh == 0) h2p[(size_t)v * 32 + c] = acc * rsq_out[v];
  }
}

// ---------------- top-k selection (2-stage bitonic) ----------------
__global__ void topk_s1(const unsigned long long* __restrict__ keys, unsigned long long* __restrict__ cand){
  __shared__ unsigned long long s[2048];
  int b = blockIdx.x >> 3, ch = blockIdx.x & 7;
  int t = threadIdx.x;            // 256
  for (int i = t; i < 2048; i += 256) s[i] = keys[(size_t)b * NKEY_ + (size_t)ch * 2048 + i];
  for (int k2 = 2; k2 <= 2048; k2 <<= 1){
    for (int j = k2 >> 1; j > 0; j >>= 1){
      __syncthreads();
      for (int i = t; i < 2048; i += 256){
        int p = i ^ j;
        if (p > i){
          unsigned long long A = s[i], C = s[p];
          bool up = ((i & k2) == 0);
          if ((A > C) == up){ s[i] = C; s[p] = A; }
        }
      }
    }
  }
  __syncthreads();
  if (t < 64) cand[(size_t)b * 512 + (size_t)ch * 64 + t] = s[t];
}

__global__ void topk_s2(const unsigned long long* __restrict__ cand, int* __restrict__ topidx){
  __shared__ unsigned long long s[512];
  int b = blockIdx.x;
  int t = threadIdx.x;            // 256
  for (int i = t; i < 512; i += 256) s[i] = cand[(size_t)b * 512 + i];
  for (int k2 = 2; k2 <= 512; k2 <<= 1){
    for (int j = k2 >> 1; j > 0; j >>= 1){
      __syncthreads();
      for (int i = t; i < 512; i += 256){
        int p = i ^ j;
        if (p > i){
          unsigned long long A = s[i], C = s[p];
          bool up = ((i & k2) == 0);
          if ((A > C) == up){ s[i] = C; s[p] = A; }
        }
      }
    }
  }
  __syncthreads();
  if (t < 64) topidx[b * 64 + t] = (int)(s[t] & 0xFFFFFFFFull);
}

// normalize selected raw h1 rows on the fly, sort 128 ascending, final leaky, write
__global__ void emit1(const float* __restrict__ h1, const int* __restrict__ topidx,
                      const float* __restrict__ mul, const float* __restrict__ add,
                      float* __restrict__ out){
  __shared__ float s[128];
  int b = blockIdx.x >> 6, k = blockIdx.x & 63;
  int t = threadIdx.x;            // 128
  int nloc = topidx[b * 64 + k];
  float raw = h1[((size_t)b * NPG_ + nloc) * 128 + t];
  s[t] = lrelu(fmaf(mul[b * 128 + t], raw, add[b * 128 + t]));
  for (int k2 = 2; k2 <= 128; k2 <<= 1){
    for (int j = k2 >> 1; j > 0; j >>= 1){
      __syncthreads();
      int p = t ^ j;
      if (p > t){
        float A = s[t], C = s[p];
        bool up = ((t & k2) == 0);
        if ((A > C) == up){ s[t] = C; s[p] = A; }
      }
    }
  }
  __syncthreads();
  out[(size_t)b * OUT_ROW + (size_t)k * 128 + t] = lrelu(s[t]);
}

// ---------------- layer 2: SpMM on projected h2p (32-d rows) ----------------
// h2c[v][c] = rsq_in[v] * sum_e csr_w * h2p[src][c]
__global__ void spmm2_fused(const int* __restrict__ off, const int* __restrict__ cnt,
                            const int* __restrict__ csr_src, const float* __restrict__ csr_w,
                            const float* __restrict__ rsq_in, const float* __restrict__ h2p,
                            float* __restrict__ h2c){
  int t    = threadIdx.x;
  int g    = blockIdx.x & 7;
  int r    = (blockIdx.x >> 3) * 4 + (t >> 6);
  int lane = t & 63;
  int c    = lane & 31, hh = lane >> 5;
  int v0   = g * NPG_ + r * CHUNK_;
  int vend = imin(v0 + CHUNK_, (g + 1) * NPG_);

  for (int v = v0; v < vend; ++v){
    int s0 = __builtin_amdgcn_readfirstlane(off[v]);
    int n  = __builtin_amdgcn_readfirstlane(cnt[v]);
    float acc = 0.f;
    for (int e0 = 0; e0 < n; e0 += 64){
      int batch = n - e0; if (batch > 64) batch = 64;
      int ms = 0; float mw = 0.f;
      if (lane < batch){
        ms = csr_src[s0 + e0 + lane];
        mw = csr_w [s0 + e0 + lane];
      }
      // two edges per iteration: lower half-wave takes edge j, upper takes j+1
      for (int j = 0; j < batch; j += 2){
        int   sA = rlanei(ms, j);
        float wA = rlanef(mw, j);
        int jb = j + 1; if (jb > 63) jb = 63;       // clamp (lane holds 0 weight if >= batch)
        int   sB = rlanei(ms, jb);
        float wB = rlanef(mw, jb);
        int   s  = hh ? sB : sA;
        float wg = hh ? wB : wA;
        acc = fmaf(wg, h2p[(size_t)s * 32 + c], acc);
      }
    }
    acc += __shfl_xor(acc, 32);
    if (hh == 0) h2c[(size_t)v * 32 + c] = acc * rsq_in[v];
  }
}

__global__ void stats2(const float* __restrict__ h, float* __restrict__ gsum, float* __restrict__ gsq){
  int b = blockIdx.x / 25, chunk = blockIdx.x % 25;
  int t = threadIdx.x;
  int c = t & 31, r0 = t >> 5;
  size_t base = ((size_t)b * NPG_ + (size_t)chunk * 500) * 32;
  float s = 0.f, q = 0.f;
  for (int r = r0; r < 500; r += 8){
    float v = h[base + (size_t)r * 32 + c];
    s += v; q += v * v;
  }
  __shared__ float ls[256], lq[256];
  ls[t] = s; lq[t] = q;
  __syncthreads();
  if (t < 32){
    float S = 0.f, Q = 0.f;
    for (int i = 0; i < 8; ++i){ S += ls[t + 32 * i]; Q += lq[t + 32 * i]; }
    atomicAdd(&gsum[b * 32 + t], S);
    atomicAdd(&gsq [b * 32 + t], Q);
  }
}

__global__ void finalize2(const float* __restrict__ gsum, const float* __restrict__ gsq,
                          const float* __restrict__ gamma, const float* __restrict__ beta,
                          const float* __restrict__ alpha, float* __restrict__ mul, float* __restrict__ add){
  int i = threadIdx.x;            // 256 = 8*32
  int c = i & 31;
  const float invn = 1.0f / (float)NPG_;
  float m = gsum[i] * invn;
  float a = alpha[c];
  float var = gsq[i] * invn - 2.f * a * m * m + a * a * m * m;
  float mu = gamma[c] * rsqrtf(var + 1e-5f);
  mul[i] = mu;
  add[i] = beta[c] - mu * a * m;
}

__global__ void norm2(float* __restrict__ h, const float* __restrict__ mul, const float* __restrict__ add,
                      unsigned long long* __restrict__ keys){
  int tid  = blockIdx.x * 256 + threadIdx.x;
  int node = tid >> 5;
  int sl   = tid & 31;
  if (node >= TOTAL_N_) return;
  int b = node / NPG_;
  int nloc = node - b * NPG_;
  float v = h[(size_t)node * 32 + sl];
  v = lrelu(fmaf(mul[b * 32 + sl], v, add[b * 32 + sl]));
  h[(size_t)node * 32 + sl] = v;
  float m = v;
  for (int o = 1; o < 32; o <<= 1) m = fmaxf(m, __shfl_xor(m, o));
  if (sl == 0){
    unsigned u = __float_as_uint(m);
    u ^= (u >> 31) ? 0xFFFFFFFFu : 0x80000000u;
    keys[(size_t)b * NKEY_ + nloc] = ((unsigned long long)(~u) << 32) | (unsigned)nloc;
  }
}

__global__ void emit2(const float* __restrict__ h2, const int* __restrict__ topidx, float* __restrict__ out){
  int b = blockIdx.x >> 6, k = blockIdx.x & 63;
  int lane = threadIdx.x;         // 32
  int nloc = topidx[b * 64 + k];
  float v = h2[((size_t)b * NPG_ + nloc) * 32 + lane];
  for (int k2 = 2; k2 <= 32; k2 <<= 1){
    for (int j = k2 >> 1; j > 0; j >>= 1){
      float o = __shfl_xor(v, j);
      bool up    = ((lane & k2) == 0);
      bool lower = ((lane & j) == 0);
      v = (up == lower) ? fminf(v, o) : fmaxf(v, o);
    }
  }
  out[(size_t)b * OUT_ROW + 8192 + (size_t)k * 32 + lane] = lrelu(v);
}

__global__ void sentinel_kernel(float* out){
  int i = blockIdx.x * 256 + threadIdx.x;
  if (i < B_ * OUT_ROW) out[i] = -777.0f;
}

extern "C" void kernel_launch(void* const* d_in, const int* in_sizes, int n_in,
                              void* d_out, int out_size, void* d_ws, size_t ws_size,
                              hipStream_t stream){
  const float* feat   = (const float*)d_in[0];
  const float* ew     = (const float*)d_in[1];
  const float* W1     = (const float*)d_in[2];
  const float* W2     = (const float*)d_in[3];
  const float* gamma1 = (const float*)d_in[4];
  const float* beta1  = (const float*)d_in[5];
  const float* alpha1 = (const float*)d_in[6];
  const float* gamma2 = (const float*)d_in[7];
  const float* beta2  = (const float*)d_in[8];
  const float* alpha2 = (const float*)d_in[9];
  const int*   esrc   = (const int*)d_in[10];
  const int*   edst   = (const int*)d_in[11];
  float* out = (float*)d_out;

  char* ws = (char*)d_ws;
  auto alloc = [&](size_t bytes) -> char* {
    char* p = ws;
    ws += (bytes + 255) & ~(size_t)255;
    return p;
  };

  // zeroed region (must stay first & contiguous)
  int*   in_cnt  = (int*)  alloc((size_t)TOTAL_N_ * 4);
  int*   out_cnt = (int*)  alloc((size_t)TOTAL_N_ * 4);
  int*   cursor  = (int*)  alloc((size_t)TOTAL_N_ * 4);
  float* gsum1   = (float*)alloc(1024 * 4);
  float* gsq1    = (float*)alloc(1024 * 4);
  float* gsum2   = (float*)alloc(256 * 4);
  float* gsq2    = (float*)alloc(256 * 4);
  size_t zero_bytes = (size_t)(ws - (char*)d_ws);

  float* rsq_in  = (float*)alloc((size_t)TOTAL_N_ * 4);
  float* rsq_out = (float*)alloc((size_t)TOTAL_N_ * 4);
  int*   off     = (int*)  alloc((size_t)TOTAL_N_ * 4);
  int*   bsum    = (int*)  alloc(512 * 4);
  float* mul1    = (float*)alloc(1024 * 4);
  float* add1    = (float*)alloc(1024 * 4);
  float* mul2    = (float*)alloc(256 * 4);
  float* add2    = (float*)alloc(256 * 4);
  int*   topidx1 = (int*)  alloc(512 * 4);
  int*   topidx2 = (int*)  alloc(512 * 4);
  unsigned long long* cand = (unsigned long long*)alloc((size_t)B_ * 512 * 8);
  unsigned long long* keys = (unsigned long long*)alloc((size_t)B_ * NKEY_ * 8);
  int*   csr_src = (int*)  alloc((size_t)TOTAL_E_ * 4);
  float* csr_w   = (float*)alloc((size_t)TOTAL_E_ * 4);
  float* csr_wr  = (float*)alloc((size_t)TOTAL_E_ * 4);
  float* h2p     = (float*)alloc((size_t)TOTAL_N_ * 32 * 4);
  float* h2c     = (float*)alloc((size_t)TOTAL_N_ * 32 * 4);
  float* h1      = (float*)alloc((size_t)TOTAL_N_ * 128 * 4);

  size_t need = (size_t)(ws - (char*)d_ws);
  if (need > ws_size){
    sentinel_kernel<<<(B_ * OUT_ROW + 255) / 256, 256, 0, stream>>>(out);
    return;
  }

  hipMemsetAsync(d_ws, 0, zero_bytes, stream);
  hipMemsetAsync(keys, 0xFF, (size_t)B_ * NKEY_ * 8, stream);

  deg_kernel <<<(TOTAL_E_ + 255) / 256, 256, 0, stream>>>(esrc, edst, out_cnt, in_cnt);
  rsq_kernel <<<NB_SCAN, 256, 0, stream>>>(in_cnt, out_cnt, rsq_in, rsq_out);
  scan_blocks<<<NB_SCAN, 256, 0, stream>>>(in_cnt, off, bsum);
  scan_sums  <<<1, 512, 0, stream>>>(bsum, NB_SCAN);
  scan_add   <<<NB_SCAN, 256, 0, stream>>>(off, bsum);
  fill_csr   <<<(TOTAL_E_ + 255) / 256, 256, 0, stream>>>(esrc, edst, ew, rsq_out, off, cursor,
                                                          csr_src, csr_w, csr_wr);

  // layer 1
  spmm1_fused<<<NBLK_, 256, 0, stream>>>(off, in_cnt, csr_src, csr_wr, feat, W1, rsq_in, h1);
  stats1     <<<200, 256, 0, stream>>>(h1, gsum1, gsq1);
  finalize1  <<<1, 1024, 0, stream>>>(gsum1, gsq1, gamma1, beta1, alpha1, mul1, add1);
  normproj   <<<NBLK_, 256, 0, stream>>>(h1, mul1, add1, rsq_out, W2, keys, h2p);
  topk_s1    <<<B_ * 8, 256, 0, stream>>>(keys, cand);
  topk_s2    <<<B_, 256, 0, stream>>>(cand, topidx1);
  emit1      <<<B_ * 64, 128, 0, stream>>>(h1, topidx1, mul1, add1, out);

  // layer 2
  spmm2_fused<<<NBLK_, 256, 0, stream>>>(off, in_cnt, csr_src, csr_w, rsq_in, h2p, h2c);
  stats2     <<<200, 256, 0, stream>>>(h2c, gsum2, gsq2);
  finalize2  <<<1, 256, 0, stream>>>(gsum2, gsq2, gamma2, beta2, alpha2, mul2, add2);
  norm2      <<<TOTAL_N_ * 32 / 256, 256, 0, stream>>>(h2c, mul2, add2, keys);
  topk_s1    <<<B_ * 8, 256, 0, stream>>>(keys, cand);
  topk_s2    <<<B_, 256, 0, stream>>>(cand, topidx2);
  emit2      <<<B_ * 64, 32, 0, stream>>>(h2c, topidx2, out);
}

// Round 3
// 806.618 us; speedup vs baseline: 1.5979x; 1.5979x over previous
//
#include <hip/hip_runtime.h>
#include <cstdint>

// ---- problem constants ----
constexpr int B_       = 8;
constexpr int NPG_     = 12500;    // nodes per graph
constexpr int KSEL_    = 64;       // sort-pool k
constexpr int TOTAL_N_ = 100000;
constexpr int TOTAL_E_ = 1600000;
constexpr int NKEY_    = 16384;    // padded per-graph key count (pow2 >= NPG_)
constexpr int NB_SCAN  = (TOTAL_N_ + 255) / 256;   // 391
constexpr int OUT_ROW  = KSEL_ * (128 + 32);       // 10240
constexpr int NBLK_    = 1024;     // 4 blocks/CU, all co-resident
constexpr int WSTRIDE_ = 512;      // wave slots per graph (1024 blocks * 4 waves / 8 graphs)

__device__ __forceinline__ float lrelu(float v){ return v >= 0.f ? v : 0.01f * v; }
__device__ __forceinline__ int   rlanei(int x, int l){ return __builtin_amdgcn_readlane(x, l); }
__device__ __forceinline__ float rlanef(float x, int l){
  return __uint_as_float(__builtin_amdgcn_readlane((int)__float_as_uint(x), l));
}

// ---------------- degrees ----------------
__global__ void deg_kernel(const int* __restrict__ src, const int* __restrict__ dst,
                           int* __restrict__ out_cnt, int* __restrict__ in_cnt){
  int i = blockIdx.x * 256 + threadIdx.x;
  if (i < TOTAL_E_){
    atomicAdd(&out_cnt[src[i]], 1);
    atomicAdd(&in_cnt[dst[i]], 1);
  }
}

__global__ void rsq_kernel(const int* __restrict__ in_cnt, const int* __restrict__ out_cnt,
                           float* __restrict__ rsq_in, float* __restrict__ rsq_out){
  int i = blockIdx.x * 256 + threadIdx.x;
  if (i < TOTAL_N_){
    int ic = in_cnt[i];  if (ic < 1) ic = 1;
    int oc = out_cnt[i]; if (oc < 1) oc = 1;
    rsq_in[i]  = rsqrtf((float)ic);
    rsq_out[i] = rsqrtf((float)oc);
  }
}

// ---------------- exclusive scan (3 kernels) ----------------
__global__ void scan_blocks(const int* __restrict__ cnt, int* __restrict__ off, int* __restrict__ bsum){
  __shared__ int tmp[256];
  int t = threadIdx.x;
  int i = blockIdx.x * 256 + t;
  int x = (i < TOTAL_N_) ? cnt[i] : 0;
  tmp[t] = x;
  __syncthreads();
  for (int d = 1; d < 256; d <<= 1){
    int v = (t >= d) ? tmp[t - d] : 0;
    __syncthreads();
    tmp[t] += v;
    __syncthreads();
  }
  if (i < TOTAL_N_) off[i] = tmp[t] - x;
  if (t == 255) bsum[blockIdx.x] = tmp[255];
}

__global__ void scan_sums(int* __restrict__ bsum, int nb){
  __shared__ int tmp[512];
  int t = threadIdx.x;
  int x = (t < nb) ? bsum[t] : 0;
  tmp[t] = x;
  __syncthreads();
  for (int d = 1; d < 512; d <<= 1){
    int v = (t >= d) ? tmp[t - d] : 0;
    __syncthreads();
    tmp[t] += v;
    __syncthreads();
  }
  if (t < nb) bsum[t] = tmp[t] - x;
}

__global__ void scan_add(int* __restrict__ off, const int* __restrict__ bsum){
  int i = blockIdx.x * 256 + threadIdx.x;
  if (i < TOTAL_N_) off[i] += bsum[blockIdx.x];
}

// ---------------- CSR fill (bucket by dst) ----------------
__global__ void fill_csr(const int* __restrict__ src, const int* __restrict__ dst,
                         const float* __restrict__ ew, const float* __restrict__ rsq_out,
                         const int* __restrict__ off, int* __restrict__ cursor,
                         int* __restrict__ csr_src, float* __restrict__ csr_w,
                         float* __restrict__ csr_wr){
  int i = blockIdx.x * 256 + threadIdx.x;
  if (i < TOTAL_E_){
    int s = src[i];
    int d = dst[i];
    float w = ew[i];
    int p = atomicAdd(&cursor[d], 1);
    int slot = off[d] + p;
    csr_src[slot] = s;
    csr_w[slot]   = w;
    csr_wr[slot]  = w * rsq_out[s];
  }
}

// ---------------- layer 1: fused SpMM (64-d) + W1 projection ----------------
// h1_raw[v][c] = rsq_in[v] * sum_k ( sum_e csr_wr * feat[src][k] ) * W1[k][c]
__global__ __launch_bounds__(256, 4)
void spmm1_fused(const int* __restrict__ off, const int* __restrict__ cnt,
                 const int* __restrict__ csr_src, const float* __restrict__ csr_wr,
                 const float* __restrict__ feat, const float* __restrict__ W1,
                 const float* __restrict__ rsq_in, float* __restrict__ h1){
  __shared__ float wsh[64 * 128];   // 32 KB, loaded once per block
  int t = threadIdx.x;
  for (int i = t; i < 64 * 128; i += 256) wsh[i] = W1[i];
  __syncthreads();

  int g     = blockIdx.x & 7;                       // graph == XCD chunk
  int wslot = (blockIdx.x >> 3) * 4 + (t >> 6);     // 0..511
  int lane  = t & 63;

  // preload this wave's node metadata: lane i holds off/cnt of node (wslot + i*WSTRIDE_)
  int pof = 0, pcn = 0;
  {
    int nl = wslot + lane * WSTRIDE_;
    if (lane < 32 && nl < NPG_){
      int v = g * NPG_ + nl;
      pof = off[v];
      pcn = cnt[v];
    }
  }
  int nv = (NPG_ - wslot + WSTRIDE_ - 1) / WSTRIDE_;   // 24 or 25

  // csr batch prefetch pipeline
  int ms = 0, msn = 0; float mw = 0.f, mwn = 0.f;
  {
    int sb = rlanei(pof, 0);
    int n  = rlanei(pcn, 0);
    int b  = n < 64 ? n : 64;
    if (lane < b){ ms = csr_src[sb + lane]; mw = csr_wr[sb + lane]; }
  }

  for (int i = 0; i < nv; ++i){
    int sbase = rlanei(pof, i);
    int n     = rlanei(pcn, i);
    int batch = n < 64 ? n : 64;
    // issue next node's csr batch now; consumed next iteration
    if (i + 1 < nv){
      int sb = rlanei(pof, i + 1);
      int n1 = rlanei(pcn, i + 1);
      int b1 = n1 < 64 ? n1 : 64;
      msn = 0; mwn = 0.f;
      if (lane < b1){ msn = csr_src[sb + lane]; mwn = csr_wr[sb + lane]; }
    }

    float acc = 0.f;
    int j = 0;
    #pragma unroll 1
    for (; j + 8 <= batch; j += 8){
      int   s0 = rlanei(ms, j+0), s1 = rlanei(ms, j+1), s2 = rlanei(ms, j+2), s3 = rlanei(ms, j+3);
      int   s4 = rlanei(ms, j+4), s5 = rlanei(ms, j+5), s6 = rlanei(ms, j+6), s7 = rlanei(ms, j+7);
      float w0 = rlanef(mw, j+0), w1 = rlanef(mw, j+1), w2 = rlanef(mw, j+2), w3 = rlanef(mw, j+3);
      float w4 = rlanef(mw, j+4), w5 = rlanef(mw, j+5), w6 = rlanef(mw, j+6), w7 = rlanef(mw, j+7);
      float f0 = feat[(size_t)s0 * 64 + lane];
      float f1 = feat[(size_t)s1 * 64 + lane];
      float f2 = feat[(size_t)s2 * 64 + lane];
      float f3 = feat[(size_t)s3 * 64 + lane];
      float f4 = feat[(size_t)s4 * 64 + lane];
      float f5 = feat[(size_t)s5 * 64 + lane];
      float f6 = feat[(size_t)s6 * 64 + lane];
      float f7 = feat[(size_t)s7 * 64 + lane];
      acc = fmaf(w0, f0, acc); acc = fmaf(w1, f1, acc);
      acc = fmaf(w2, f2, acc); acc = fmaf(w3, f3, acc);
      acc = fmaf(w4, f4, acc); acc = fmaf(w5, f5, acc);
      acc = fmaf(w6, f6, acc); acc = fmaf(w7, f7, acc);
    }
    #pragma unroll 1
    for (; j < batch; ++j){
      acc = fmaf(rlanef(mw, j), feat[(size_t)rlanei(ms, j) * 64 + lane], acc);
    }
    if (n > 64){   // statistically never (Poisson mean 16), correctness fallback
      for (int e = 64; e < n; ++e){
        int s = csr_src[sbase + e];
        float wv = csr_wr[sbase + e];
        acc = fmaf(wv, feat[(size_t)s * 64 + lane], acc);
      }
    }

    // epilogue: project 64 -> 128; lane owns columns 2*lane, 2*lane+1
    float2 a = make_float2(0.f, 0.f);
    const float2* wp = (const float2*)wsh;
    #pragma unroll
    for (int k = 0; k < 64; ++k){
      float ak = rlanef(acc, k);
      float2 wv = wp[k * 64 + lane];
      a.x = fmaf(ak, wv.x, a.x);
      a.y = fmaf(ak, wv.y, a.y);
    }
    int v = g * NPG_ + wslot + i * WSTRIDE_;
    float ri = rsq_in[v];
    a.x *= ri; a.y *= ri;
    *(float2*)&h1[(size_t)v * 128 + 2 * lane] = a;

    ms = msn; mw = mwn;
  }
}

// per-(graph,channel) sum & sumsq over RAW h1, D=128
__global__ void stats1(const float* __restrict__ h, float* __restrict__ gsum, float* __restrict__ gsq){
  int b = blockIdx.x / 25, chunk = blockIdx.x % 25;
  int t = threadIdx.x;
  int c = t & 127, r0 = t >> 7;
  size_t base = ((size_t)b * NPG_ + (size_t)chunk * 500) * 128;
  float s = 0.f, q = 0.f;
  for (int r = r0; r < 500; r += 2){
    float v = h[base + (size_t)r * 128 + c];
    s += v; q += v * v;
  }
  __shared__ float ls[256], lq[256];
  ls[t] = s; lq[t] = q;
  __syncthreads();
  if (t < 128){
    s = ls[t] + ls[t + 128];
    q = lq[t] + lq[t + 128];
    atomicAdd(&gsum[b * 128 + c], s);
    atomicAdd(&gsq [b * 128 + c], q);
  }
}

__global__ void finalize1(const float* __restrict__ gsum, const float* __restrict__ gsq,
                          const float* __restrict__ gamma, const float* __restrict__ beta,
                          const float* __restrict__ alpha, float* __restrict__ mul, float* __restrict__ add){
  int i = threadIdx.x;            // 1024 = 8*128
  int c = i & 127;
  const float invn = 1.0f / (float)NPG_;
  float m = gsum[i] * invn;
  float a = alpha[c];
  float var = gsq[i] * invn - 2.f * a * m * m + a * a * m * m;
  float mu = gamma[c] * rsqrtf(var + 1e-5f);
  mul[i] = mu;
  add[i] = beta[c] - mu * a * m;
}

// ---------------- fused: normalize h1 (in regs) + sort keys + project to h2p ----------------
// h1 stays RAW in memory. h2p[v][c] = rsq_out[v] * sum_k lrelu(norm(h1))[k] * W2[k][c]
__global__ __launch_bounds__(256, 4)
void normproj(const float* __restrict__ h1,
              const float* __restrict__ mul, const float* __restrict__ add,
              const float* __restrict__ rsq_out, const float* __restrict__ W2,
              unsigned long long* __restrict__ keys, float* __restrict__ h2p){
  __shared__ float w2s[128 * 32];  // 16 KB
  int t = threadIdx.x;
  for (int i = t; i < 128 * 32; i += 256) w2s[i] = W2[i];
  __syncthreads();

  int g     = blockIdx.x & 7;
  int wslot = (blockIdx.x >> 3) * 4 + (t >> 6);
  int lane  = t & 63;
  int c     = lane & 31, hh = lane >> 5;
  int wbase = hh * 64 * 32 + c;

  float m0 = mul[g * 128 + lane],      aa0 = add[g * 128 + lane];
  float m1 = mul[g * 128 + 64 + lane], aa1 = add[g * 128 + 64 + lane];

  int nv = (NPG_ - wslot + WSTRIDE_ - 1) / WSTRIDE_;

  // pipelined row loads
  int v0 = g * NPG_ + wslot;
  float x0 = h1[(size_t)v0 * 128 + lane];
  float x1 = h1[(size_t)v0 * 128 + 64 + lane];

  for (int i = 0; i < nv; ++i){
    int v = g * NPG_ + wslot + i * WSTRIDE_;
    float cur0 = x0, cur1 = x1;
    if (i + 1 < nv){
      int vn = v + WSTRIDE_;
      x0 = h1[(size_t)vn * 128 + lane];
      x1 = h1[(size_t)vn * 128 + 64 + lane];
    }
    float y0 = lrelu(fmaf(m0, cur0, aa0));
    float y1 = lrelu(fmaf(m1, cur1, aa1));
    // sort key: max channel (descending value, ascending index tie-break)
    float mx = fmaxf(y0, y1);
    for (int o = 1; o < 64; o <<= 1) mx = fmaxf(mx, __shfl_xor(mx, o));
    if (lane == 0){
      unsigned u = __float_as_uint(mx);
      u ^= (u >> 31) ? 0xFFFFFFFFu : 0x80000000u;
      int nloc = v - g * NPG_;
      keys[(size_t)g * NKEY_ + nloc] = ((unsigned long long)(~u) << 32) | (unsigned)nloc;
    }
    // project 128 -> 32: lanes 0..31 take k=0..63, lanes 32..63 take k=64..127
    float acc = 0.f;
    #pragma unroll
    for (int kk = 0; kk < 64; ++kk){
      float sa = rlanef(y0, kk);
      float sb = rlanef(y1, kk);
      float vk = hh ? sb : sa;
      acc = fmaf(vk, w2s[wbase + kk * 32], acc);
    }
    acc += __shfl_xor(acc, 32);
    if (hh == 0) h2p[(size_t)v * 32 + c] = acc * rsq_out[v];
  }
}

// ---------------- top-k selection (2-stage bitonic) ----------------
__global__ void topk_s1(const unsigned long long* __restrict__ keys, unsigned long long* __restrict__ cand){
  __shared__ unsigned long long s[2048];
  int b = blockIdx.x >> 3, ch = blockIdx.x & 7;
  int t = threadIdx.x;            // 256
  for (int i = t; i < 2048; i += 256) s[i] = keys[(size_t)b * NKEY_ + (size_t)ch * 2048 + i];
  for (int k2 = 2; k2 <= 2048; k2 <<= 1){
    for (int j = k2 >> 1; j > 0; j >>= 1){
      __syncthreads();
      for (int i = t; i < 2048; i += 256){
        int p = i ^ j;
        if (p > i){
          unsigned long long A = s[i], C = s[p];
          bool up = ((i & k2) == 0);
          if ((A > C) == up){ s[i] = C; s[p] = A; }
        }
      }
    }
  }
  __syncthreads();
  if (t < 64) cand[(size_t)b * 512 + (size_t)ch * 64 + t] = s[t];
}

__global__ void topk_s2(const unsigned long long* __restrict__ cand, int* __restrict__ topidx){
  __shared__ unsigned long long s[512];
  int b = blockIdx.x;
  int t = threadIdx.x;            // 256
  for (int i = t; i < 512; i += 256) s[i] = cand[(size_t)b * 512 + i];
  for (int k2 = 2; k2 <= 512; k2 <<= 1){
    for (int j = k2 >> 1; j > 0; j >>= 1){
      __syncthreads();
      for (int i = t; i < 512; i += 256){
        int p = i ^ j;
        if (p > i){
          unsigned long long A = s[i], C = s[p];
          bool up = ((i & k2) == 0);
          if ((A > C) == up){ s[i] = C; s[p] = A; }
        }
      }
    }
  }
  __syncthreads();
  if (t < 64) topidx[b * 64 + t] = (int)(s[t] & 0xFFFFFFFFull);
}

// normalize selected raw h1 rows on the fly, sort 128 ascending, final leaky, write
__global__ void emit1(const float* __restrict__ h1, const int* __restrict__ topidx,
                      const float* __restrict__ mul, const float* __restrict__ add,
                      float* __restrict__ out){
  __shared__ float s[128];
  int b = blockIdx.x >> 6, k = blockIdx.x & 63;
  int t = threadIdx.x;            // 128
  int nloc = topidx[b * 64 + k];
  float raw = h1[((size_t)b * NPG_ + nloc) * 128 + t];
  s[t] = lrelu(fmaf(mul[b * 128 + t], raw, add[b * 128 + t]));
  for (int k2 = 2; k2 <= 128; k2 <<= 1){
    for (int j = k2 >> 1; j > 0; j >>= 1){
      __syncthreads();
      int p = t ^ j;
      if (p > t){
        float A = s[t], C = s[p];
        bool up = ((t & k2) == 0);
        if ((A > C) == up){ s[t] = C; s[p] = A; }
      }
    }
  }
  __syncthreads();
  out[(size_t)b * OUT_ROW + (size_t)k * 128 + t] = lrelu(s[t]);
}

// ---------------- layer 2: SpMM on projected h2p (32-d rows) ----------------
// h2c[v][c] = rsq_in[v] * sum_e csr_w * h2p[src][c]
__global__ __launch_bounds__(256, 4)
void spmm2_fused(const int* __restrict__ off, const int* __restrict__ cnt,
                 const int* __restrict__ csr_src, const float* __restrict__ csr_w,
                 const float* __restrict__ rsq_in, const float* __restrict__ h2p,
                 float* __restrict__ h2c){
  int t     = threadIdx.x;
  int g     = blockIdx.x & 7;
  int wslot = (blockIdx.x >> 3) * 4 + (t >> 6);
  int lane  = t & 63;
  int c     = lane & 31, hh = lane >> 5;

  int pof = 0, pcn = 0;
  {
    int nl = wslot + lane * WSTRIDE_;
    if (lane < 32 && nl < NPG_){
      int v = g * NPG_ + nl;
      pof = off[v];
      pcn = cnt[v];
    }
  }
  int nv = (NPG_ - wslot + WSTRIDE_ - 1) / WSTRIDE_;

  int ms = 0, msn = 0; float mw = 0.f, mwn = 0.f;
  {
    int sb = rlanei(pof, 0);
    int n  = rlanei(pcn, 0);
    int b  = n < 64 ? n : 64;
    if (lane < b){ ms = csr_src[sb + lane]; mw = csr_w[sb + lane]; }
  }

  for (int i = 0; i < nv; ++i){
    int sbase = rlanei(pof, i);
    int n     = rlanei(pcn, i);
    int batch = n < 64 ? n : 64;
    if (i + 1 < nv){
      int sb = rlanei(pof, i + 1);
      int n1 = rlanei(pcn, i + 1);
      int b1 = n1 < 64 ? n1 : 64;
      msn = 0; mwn = 0.f;
      if (lane < b1){ msn = csr_src[sb + lane]; mwn = csr_w[sb + lane]; }
    }

    float acc = 0.f;
    int j = 0;
    #pragma unroll 1
    for (; j + 8 <= batch; j += 8){
      int   sa0 = rlanei(ms, j+0), sb0 = rlanei(ms, j+1);
      int   sa1 = rlanei(ms, j+2), sb1 = rlanei(ms, j+3);
      int   sa2 = rlanei(ms, j+4), sb2 = rlanei(ms, j+5);
      int   sa3 = rlanei(ms, j+6), sb3 = rlanei(ms, j+7);
      float wa0 = rlanef(mw, j+0), wb0 = rlanef(mw, j+1);
      float wa1 = rlanef(mw, j+2), wb1 = rlanef(mw, j+3);
      float wa2 = rlanef(mw, j+4), wb2 = rlanef(mw, j+5);
      float wa3 = rlanef(mw, j+6), wb3 = rlanef(mw, j+7);
      int   s0 = hh ? sb0 : sa0;  float g0 = hh ? wb0 : wa0;
      int   s1 = hh ? sb1 : sa1;  float g1 = hh ? wb1 : wa1;
      int   s2 = hh ? sb2 : sa2;  float g2 = hh ? wb2 : wa2;
      int   s3 = hh ? sb3 : sa3;  float g3 = hh ? wb3 : wa3;
      float f0 = h2p[(size_t)s0 * 32 + c];
      float f1 = h2p[(size_t)s1 * 32 + c];
      float f2 = h2p[(size_t)s2 * 32 + c];
      float f3 = h2p[(size_t)s3 * 32 + c];
      acc = fmaf(g0, f0, acc); acc = fmaf(g1, f1, acc);
      acc = fmaf(g2, f2, acc); acc = fmaf(g3, f3, acc);
    }
    #pragma unroll 1
    for (; j < batch; j += 2){
      int jb = j + 1; if (jb > 63) jb = 63;   // lane jb holds 0 weight if >= batch
      int   sA = rlanei(ms, j);  float wA = rlanef(mw, j);
      int   sB = rlanei(ms, jb); float wB = rlanef(mw, jb);
      int   s  = hh ? sB : sA;
      float wg = hh ? wB : wA;
      acc = fmaf(wg, h2p[(size_t)s * 32 + c], acc);
    }
    acc += __shfl_xor(acc, 32);
    if (n > 64){   // correctness fallback, uniform loads, counted once
      for (int e = 64; e < n; ++e){
        int s = csr_src[sbase + e];
        float wv = csr_w[sbase + e];
        acc = fmaf(wv, h2p[(size_t)s * 32 + c], acc);
      }
    }
    int v = g * NPG_ + wslot + i * WSTRIDE_;
    if (hh == 0) h2c[(size_t)v * 32 + c] = acc * rsq_in[v];

    ms = msn; mw = mwn;
  }
}

__global__ void stats2(const float* __restrict__ h, float* __restrict__ gsum, float* __restrict__ gsq){
  int b = blockIdx.x / 25, chunk = blockIdx.x % 25;
  int t = threadIdx.x;
  int c = t & 31, r0 = t >> 5;
  size_t base = ((size_t)b * NPG_ + (size_t)chunk * 500) * 32;
  float s = 0.f, q = 0.f;
  for (int r = r0; r < 500; r += 8){
    float v = h[base + (size_t)r * 32 + c];
    s += v; q += v * v;
  }
  __shared__ float ls[256], lq[256];
  ls[t] = s; lq[t] = q;
  __syncthreads();
  if (t < 32){
    float S = 0.f, Q = 0.f;
    for (int i = 0; i < 8; ++i){ S += ls[t + 32 * i]; Q += lq[t + 32 * i]; }
    atomicAdd(&gsum[b * 32 + t], S);
    atomicAdd(&gsq [b * 32 + t], Q);
  }
}

__global__ void finalize2(const float* __restrict__ gsum, const float* __restrict__ gsq,
                          const float* __restrict__ gamma, const float* __restrict__ beta,
                          const float* __restrict__ alpha, float* __restrict__ mul, float* __restrict__ add){
  int i = threadIdx.x;            // 256 = 8*32
  int c = i & 31;
  const float invn = 1.0f / (float)NPG_;
  float m = gsum[i] * invn;
  float a = alpha[c];
  float var = gsq[i] * invn - 2.f * a * m * m + a * a * m * m;
  float mu = gamma[c] * rsqrtf(var + 1e-5f);
  mul[i] = mu;
  add[i] = beta[c] - mu * a * m;
}

__global__ void norm2(float* __restrict__ h, const float* __restrict__ mul, const float* __restrict__ add,
                      unsigned long long* __restrict__ keys){
  int tid  = blockIdx.x * 256 + threadIdx.x;
  int node = tid >> 5;
  int sl   = tid & 31;
  if (node >= TOTAL_N_) return;
  int b = node / NPG_;
  int nloc = node - b * NPG_;
  float v = h[(size_t)node * 32 + sl];
  v = lrelu(fmaf(mul[b * 32 + sl], v, add[b * 32 + sl]));
  h[(size_t)node * 32 + sl] = v;
  float m = v;
  for (int o = 1; o < 32; o <<= 1) m = fmaxf(m, __shfl_xor(m, o));
  if (sl == 0){
    unsigned u = __float_as_uint(m);
    u ^= (u >> 31) ? 0xFFFFFFFFu : 0x80000000u;
    keys[(size_t)b * NKEY_ + nloc] = ((unsigned long long)(~u) << 32) | (unsigned)nloc;
  }
}

__global__ void emit2(const float* __restrict__ h2, const int* __restrict__ topidx, float* __restrict__ out){
  int b = blockIdx.x >> 6, k = blockIdx.x & 63;
  int lane = threadIdx.x;         // 32
  int nloc = topidx[b * 64 + k];
  float v = h2[((size_t)b * NPG_ + nloc) * 32 + lane];
  for (int k2 = 2; k2 <= 32; k2 <<= 1){
    for (int j = k2 >> 1; j > 0; j >>= 1){
      float o = __shfl_xor(v, j);
      bool up    = ((lane & k2) == 0);
      bool lower = ((lane & j) == 0);
      v = (up == lower) ? fminf(v, o) : fmaxf(v, o);
    }
  }
  out[(size_t)b * OUT_ROW + 8192 + (size_t)k * 32 + lane] = lrelu(v);
}

__global__ void sentinel_kernel(float* out){
  int i = blockIdx.x * 256 + threadIdx.x;
  if (i < B_ * OUT_ROW) out[i] = -777.0f;
}

extern "C" void kernel_launch(void* const* d_in, const int* in_sizes, int n_in,
                              void* d_out, int out_size, void* d_ws, size_t ws_size,
                              hipStream_t stream){
  const float* feat   = (const float*)d_in[0];
  const float* ew     = (const float*)d_in[1];
  const float* W1     = (const float*)d_in[2];
  const float* W2     = (const float*)d_in[3];
  const float* gamma1 = (const float*)d_in[4];
  const float* beta1  = (const float*)d_in[5];
  const float* alpha1 = (const float*)d_in[6];
  const float* gamma2 = (const float*)d_in[7];
  const float* beta2  = (const float*)d_in[8];
  const float* alpha2 = (const float*)d_in[9];
  const int*   esrc   = (const int*)d_in[10];
  const int*   edst   = (const int*)d_in[11];
  float* out = (float*)d_out;

  char* ws = (char*)d_ws;
  auto alloc = [&](size_t bytes) -> char* {
    char* p = ws;
    ws += (bytes + 255) & ~(size_t)255;
    return p;
  };

  // zeroed region (must stay first & contiguous)
  int*   in_cnt  = (int*)  alloc((size_t)TOTAL_N_ * 4);
  int*   out_cnt = (int*)  alloc((size_t)TOTAL_N_ * 4);
  int*   cursor  = (int*)  alloc((size_t)TOTAL_N_ * 4);
  float* gsum1   = (float*)alloc(1024 * 4);
  float* gsq1    = (float*)alloc(1024 * 4);
  float* gsum2   = (float*)alloc(256 * 4);
  float* gsq2    = (float*)alloc(256 * 4);
  size_t zero_bytes = (size_t)(ws - (char*)d_ws);

  float* rsq_in  = (float*)alloc((size_t)TOTAL_N_ * 4);
  float* rsq_out = (float*)alloc((size_t)TOTAL_N_ * 4);
  int*   off     = (int*)  alloc((size_t)TOTAL_N_ * 4);
  int*   bsum    = (int*)  alloc(512 * 4);
  float* mul1    = (float*)alloc(1024 * 4);
  float* add1    = (float*)alloc(1024 * 4);
  float* mul2    = (float*)alloc(256 * 4);
  float* add2    = (float*)alloc(256 * 4);
  int*   topidx1 = (int*)  alloc(512 * 4);
  int*   topidx2 = (int*)  alloc(512 * 4);
  unsigned long long* cand = (unsigned long long*)alloc((size_t)B_ * 512 * 8);
  unsigned long long* keys = (unsigned long long*)alloc((size_t)B_ * NKEY_ * 8);
  int*   csr_src = (int*)  alloc((size_t)TOTAL_E_ * 4);
  float* csr_w   = (float*)alloc((size_t)TOTAL_E_ * 4);
  float* csr_wr  = (float*)alloc((size_t)TOTAL_E_ * 4);
  float* h2p     = (float*)alloc((size_t)TOTAL_N_ * 32 * 4);
  float* h2c     = (float*)alloc((size_t)TOTAL_N_ * 32 * 4);
  float* h1      = (float*)alloc((size_t)TOTAL_N_ * 128 * 4);

  size_t need = (size_t)(ws - (char*)d_ws);
  if (need > ws_size){
    sentinel_kernel<<<(B_ * OUT_ROW + 255) / 256, 256, 0, stream>>>(out);
    return;
  }

  hipMemsetAsync(d_ws, 0, zero_bytes, stream);
  hipMemsetAsync(keys, 0xFF, (size_t)B_ * NKEY_ * 8, stream);

  deg_kernel <<<(TOTAL_E_ + 255) / 256, 256, 0, stream>>>(esrc, edst, out_cnt, in_cnt);
  rsq_kernel <<<NB_SCAN, 256, 0, stream>>>(in_cnt, out_cnt, rsq_in, rsq_out);
  scan_blocks<<<NB_SCAN, 256, 0, stream>>>(in_cnt, off, bsum);
  scan_sums  <<<1, 512, 0, stream>>>(bsum, NB_SCAN);
  scan_add   <<<NB_SCAN, 256, 0, stream>>>(off, bsum);
  fill_csr   <<<(TOTAL_E_ + 255) / 256, 256, 0, stream>>>(esrc, edst, ew, rsq_out, off, cursor,
                                                          csr_src, csr_w, csr_wr);

  // layer 1
  spmm1_fused<<<NBLK_, 256, 0, stream>>>(off, in_cnt, csr_src, csr_wr, feat, W1, rsq_in, h1);
  stats1     <<<200, 256, 0, stream>>>(h1, gsum1, gsq1);
  finalize1  <<<1, 1024, 0, stream>>>(gsum1, gsq1, gamma1, beta1, alpha1, mul1, add1);
  normproj   <<<NBLK_, 256, 0, stream>>>(h1, mul1, add1, rsq_out, W2, keys, h2p);
  topk_s1    <<<B_ * 8, 256, 0, stream>>>(keys, cand);
  topk_s2    <<<B_, 256, 0, stream>>>(cand, topidx1);
  emit1      <<<B_ * 64, 128, 0, stream>>>(h1, topidx1, mul1, add1, out);

  // layer 2
  spmm2_fused<<<NBLK_, 256, 0, stream>>>(off, in_cnt, csr_src, csr_w, rsq_in, h2p, h2c);
  stats2     <<<200, 256, 0, stream>>>(h2c, gsum2, gsq2);
  finalize2  <<<1, 256, 0, stream>>>(gsum2, gsq2, gamma2, beta2, alpha2, mul2, add2);
  norm2      <<<TOTAL_N_ * 32 / 256, 256, 0, stream>>>(h2c, mul2, add2, keys);
  topk_s1    <<<B_ * 8, 256, 0, stream>>>(keys, cand);
  topk_s2    <<<B_, 256, 0, stream>>>(cand, topidx2);
  emit2      <<<B_ * 64, 32, 0, stream>>>(h2c, topidx2, out);
}

// Round 4
// 781.264 us; speedup vs baseline: 1.6498x; 1.0325x over previous
//
#include <hip/hip_runtime.h>
#include <cstdint>

// ---- problem constants ----
constexpr int B_       = 8;
constexpr int NPG_     = 12500;    // nodes per graph
constexpr int KSEL_    = 64;       // sort-pool k
constexpr int TOTAL_N_ = 100000;
constexpr int TOTAL_E_ = 1600000;
constexpr int NKEY_    = 16384;    // padded per-graph key count (pow2 >= NPG_)
constexpr int NB_SCAN  = (TOTAL_N_ + 255) / 256;   // 391
constexpr int OUT_ROW  = KSEL_ * (128 + 32);       // 10240
constexpr int NBLK_    = 1024;     // 4 blocks/CU, all co-resident
constexpr int WSTRIDE_ = 512;      // wave slots per graph

typedef float f2v __attribute__((ext_vector_type(2)));

__device__ __forceinline__ float lrelu(float v){ return v >= 0.f ? v : 0.01f * v; }
__device__ __forceinline__ int   rlanei(int x, int l){ return __builtin_amdgcn_readlane(x, l); }
__device__ __forceinline__ float rlanef(float x, int l){
  return __uint_as_float(__builtin_amdgcn_readlane((int)__float_as_uint(x), l));
}

// ---------------- degrees ----------------
__global__ void deg_kernel(const int* __restrict__ src, const int* __restrict__ dst,
                           int* __restrict__ out_cnt, int* __restrict__ in_cnt){
  int i = blockIdx.x * 256 + threadIdx.x;
  if (i < TOTAL_E_){
    atomicAdd(&out_cnt[src[i]], 1);
    atomicAdd(&in_cnt[dst[i]], 1);
  }
}

__global__ void rsq_kernel(const int* __restrict__ in_cnt, const int* __restrict__ out_cnt,
                           float* __restrict__ rsq_in, float* __restrict__ rsq_out){
  int i = blockIdx.x * 256 + threadIdx.x;
  if (i < TOTAL_N_){
    int ic = in_cnt[i];  if (ic < 1) ic = 1;
    int oc = out_cnt[i]; if (oc < 1) oc = 1;
    rsq_in[i]  = rsqrtf((float)ic);
    rsq_out[i] = rsqrtf((float)oc);
  }
}

// ---------------- exclusive scan (3 kernels) ----------------
__global__ void scan_blocks(const int* __restrict__ cnt, int* __restrict__ off, int* __restrict__ bsum){
  __shared__ int tmp[256];
  int t = threadIdx.x;
  int i = blockIdx.x * 256 + t;
  int x = (i < TOTAL_N_) ? cnt[i] : 0;
  tmp[t] = x;
  __syncthreads();
  for (int d = 1; d < 256; d <<= 1){
    int v = (t >= d) ? tmp[t - d] : 0;
    __syncthreads();
    tmp[t] += v;
    __syncthreads();
  }
  if (i < TOTAL_N_) off[i] = tmp[t] - x;
  if (t == 255) bsum[blockIdx.x] = tmp[255];
}

__global__ void scan_sums(int* __restrict__ bsum, int nb){
  __shared__ int tmp[512];
  int t = threadIdx.x;
  int x = (t < nb) ? bsum[t] : 0;
  tmp[t] = x;
  __syncthreads();
  for (int d = 1; d < 512; d <<= 1){
    int v = (t >= d) ? tmp[t - d] : 0;
    __syncthreads();
    tmp[t] += v;
    __syncthreads();
  }
  if (t < nb) bsum[t] = tmp[t] - x;
}

__global__ void scan_add(int* __restrict__ off, const int* __restrict__ bsum){
  int i = blockIdx.x * 256 + threadIdx.x;
  if (i < TOTAL_N_) off[i] += bsum[blockIdx.x];
}

// ---------------- CSR fill (bucket by dst) ----------------
__global__ void fill_csr(const int* __restrict__ src, const int* __restrict__ dst,
                         const float* __restrict__ ew, const float* __restrict__ rsq_out,
                         const int* __restrict__ off, int* __restrict__ cursor,
                         int* __restrict__ csr_src, float* __restrict__ csr_w,
                         float* __restrict__ csr_wr){
  int i = blockIdx.x * 256 + threadIdx.x;
  if (i < TOTAL_E_){
    int s = src[i];
    int d = dst[i];
    float w = ew[i];
    int p = atomicAdd(&cursor[d], 1);
    int slot = off[d] + p;
    csr_src[slot] = s;
    csr_w[slot]   = w;
    csr_wr[slot]  = w * rsq_out[s];
  }
}

// ---------------- layer 1: fused SpMM (64-d) + W1 projection + stats ----------------
// h1_raw[v][c] = rsq_in[v] * sum_k ( sum_e csr_wr * feat[src][k] ) * W1[k][c]
__global__ __launch_bounds__(256, 4)
void spmm1_fused(const int* __restrict__ off, const int* __restrict__ cnt,
                 const int* __restrict__ csr_src, const float* __restrict__ csr_wr,
                 const float* __restrict__ feat, const float* __restrict__ W1,
                 const float* __restrict__ rsq_in, float* __restrict__ h1,
                 float* __restrict__ gsum, float* __restrict__ gsq){
  __shared__ float wsh[64 * 128];   // 32 KB
  __shared__ float sred[4][256];    // 4 KB stats reduce
  int t = threadIdx.x;
  for (int i = t; i < 64 * 128; i += 256) wsh[i] = W1[i];
  __syncthreads();

  int g     = blockIdx.x & 7;                       // graph == XCD (round-robin assumption)
  int wslot = (blockIdx.x >> 3) * 4 + (t >> 6);     // 0..511
  int lane  = t & 63;

  // lane i holds off/cnt of node (wslot + i*WSTRIDE_)
  int pof = 0, pcn = 0;
  {
    int nl = wslot + lane * WSTRIDE_;
    if (lane < 32 && nl < NPG_){
      int v = g * NPG_ + nl;
      pof = off[v];
      pcn = cnt[v];
    }
  }
  int nv = (NPG_ - wslot + WSTRIDE_ - 1) / WSTRIDE_;   // 24 or 25

  float s0 = 0.f, q0 = 0.f, s1 = 0.f, q1 = 0.f;        // stats accumulators (channels 2l, 2l+1)

  // pair-level csr prefetch pipeline
  int msA = 0, msB = 0, msnA = 0, msnB = 0;
  float mwA = 0.f, mwB = 0.f, mwnA = 0.f, mwnB = 0.f;
  {
    int sA = rlanei(pof, 0), nA = rlanei(pcn, 0);
    int bA = nA < 64 ? nA : 64;
    if (lane < bA){ msA = __builtin_nontemporal_load(csr_src + sA + lane);
                    mwA = __builtin_nontemporal_load(csr_wr  + sA + lane); }
    if (nv > 1){
      int sB = rlanei(pof, 1), nB = rlanei(pcn, 1);
      int bB = nB < 64 ? nB : 64;
      if (lane < bB){ msB = __builtin_nontemporal_load(csr_src + sB + lane);
                      mwB = __builtin_nontemporal_load(csr_wr  + sB + lane); }
    }
  }

  for (int i = 0; i < nv; i += 2){
    int n0 = rlanei(pcn, i);
    int b0 = n0 < 64 ? n0 : 64;
    bool has1 = (i + 1 < nv);
    int n1 = rlanei(pcn, i + 1);           // lanes >= valid hold 0
    int b1 = n1 < 64 ? n1 : 64;

    // prefetch pair i+2 / i+3
    if (i + 2 < nv){
      int sA = rlanei(pof, i + 2), nA = rlanei(pcn, i + 2);
      int bA = nA < 64 ? nA : 64;
      msnA = 0; mwnA = 0.f;
      if (lane < bA){ msnA = __builtin_nontemporal_load(csr_src + sA + lane);
                      mwnA = __builtin_nontemporal_load(csr_wr  + sA + lane); }
      msnB = 0; mwnB = 0.f;
      if (i + 3 < nv){
        int sB = rlanei(pof, i + 3), nB = rlanei(pcn, i + 3);
        int bB = nB < 64 ? nB : 64;
        if (lane < bB){ msnB = __builtin_nontemporal_load(csr_src + sB + lane);
                        mwnB = __builtin_nontemporal_load(csr_wr  + sB + lane); }
      }
    }

    // paired gather (up to 8 loads in flight); lanes >= batch carry weight 0 so
    // over-rounded sub-batches are harmless (index 0 loads node 0's row, w=0)
    float acc0 = 0.f, acc1 = 0.f;
    int jm = b0 > b1 ? b0 : b1;
    #pragma unroll 1
    for (int j = 0; j < jm; j += 4){
      float f0, f1, f2, f3, h0, h1v, h2, h3;
      float w0, w1, w2, w3, u0, u1, u2, u3;
      bool d0 = j < b0, d1 = j < b1;
      if (d0){
        int a0 = rlanei(msA, j+0), a1 = rlanei(msA, j+1), a2 = rlanei(msA, j+2), a3 = rlanei(msA, j+3);
        w0 = rlanef(mwA, j+0); w1 = rlanef(mwA, j+1); w2 = rlanef(mwA, j+2); w3 = rlanef(mwA, j+3);
        f0 = feat[(size_t)a0 * 64 + lane];
        f1 = feat[(size_t)a1 * 64 + lane];
        f2 = feat[(size_t)a2 * 64 + lane];
        f3 = feat[(size_t)a3 * 64 + lane];
      }
      if (d1){
        int a0 = rlanei(msB, j+0), a1 = rlanei(msB, j+1), a2 = rlanei(msB, j+2), a3 = rlanei(msB, j+3);
        u0 = rlanef(mwB, j+0); u1 = rlanef(mwB, j+1); u2 = rlanef(mwB, j+2); u3 = rlanef(mwB, j+3);
        h0 = feat[(size_t)a0 * 64 + lane];
        h1v = feat[(size_t)a1 * 64 + lane];
        h2 = feat[(size_t)a2 * 64 + lane];
        h3 = feat[(size_t)a3 * 64 + lane];
      }
      if (d0){
        acc0 = fmaf(w0, f0, acc0); acc0 = fmaf(w1, f1, acc0);
        acc0 = fmaf(w2, f2, acc0); acc0 = fmaf(w3, f3, acc0);
      }
      if (d1){
        acc1 = fmaf(u0, h0, acc1); acc1 = fmaf(u1, h1v, acc1);
        acc1 = fmaf(u2, h2, acc1); acc1 = fmaf(u3, h3, acc1);
      }
    }
    if (n0 > 64){   // statistically never; correctness fallback
      int sb = rlanei(pof, i);
      for (int e = 64; e < n0; ++e)
        acc0 = fmaf(csr_wr[sb + e], feat[(size_t)csr_src[sb + e] * 64 + lane], acc0);
    }
    if (has1 && n1 > 64){
      int sb = rlanei(pof, i + 1);
      for (int e = 64; e < n1; ++e)
        acc1 = fmaf(csr_wr[sb + e], feat[(size_t)csr_src[sb + e] * 64 + lane], acc1);
    }

    // paired epilogue: project 64 -> 128; lane owns columns 2*lane, 2*lane+1
    f2v A0 = {0.f, 0.f}, A1 = {0.f, 0.f};
    const f2v* wp = (const f2v*)wsh;
    #pragma unroll
    for (int k = 0; k < 64; ++k){
      f2v wv = wp[k * 64 + lane];
      float a0k = rlanef(acc0, k);
      float a1k = rlanef(acc1, k);
      A0.x = fmaf(a0k, wv.x, A0.x); A0.y = fmaf(a0k, wv.y, A0.y);
      A1.x = fmaf(a1k, wv.x, A1.x); A1.y = fmaf(a1k, wv.y, A1.y);
    }
    int v0n = g * NPG_ + wslot + i * WSTRIDE_;
    float r0 = rsq_in[v0n];
    A0.x *= r0; A0.y *= r0;
    __builtin_nontemporal_store(A0, (f2v*)&h1[(size_t)v0n * 128 + 2 * lane]);
    s0 += A0.x; q0 = fmaf(A0.x, A0.x, q0);
    s1 += A0.y; q1 = fmaf(A0.y, A0.y, q1);
    if (has1){
      int v1n = v0n + WSTRIDE_;
      float r1 = rsq_in[v1n];
      A1.x *= r1; A1.y *= r1;
      __builtin_nontemporal_store(A1, (f2v*)&h1[(size_t)v1n * 128 + 2 * lane]);
      s0 += A1.x; q0 = fmaf(A1.x, A1.x, q0);
      s1 += A1.y; q1 = fmaf(A1.y, A1.y, q1);
    }
    msA = msnA; mwA = mwnA; msB = msnB; mwB = mwnB;
  }

  // block-level stats reduce (all 4 waves same graph), then atomics
  __syncthreads();
  sred[0][t] = s0; sred[1][t] = q0; sred[2][t] = s1; sred[3][t] = q1;
  __syncthreads();
  if (t < 64){
    float S0 = sred[0][t] + sred[0][t+64] + sred[0][t+128] + sred[0][t+192];
    float Q0 = sred[1][t] + sred[1][t+64] + sred[1][t+128] + sred[1][t+192];
    float S1 = sred[2][t] + sred[2][t+64] + sred[2][t+128] + sred[2][t+192];
    float Q1 = sred[3][t] + sred[3][t+64] + sred[3][t+128] + sred[3][t+192];
    atomicAdd(&gsum[g * 128 + 2*t],     S0);
    atomicAdd(&gsq [g * 128 + 2*t],     Q0);
    atomicAdd(&gsum[g * 128 + 2*t + 1], S1);
    atomicAdd(&gsq [g * 128 + 2*t + 1], Q1);
  }
}

__global__ void finalize1(const float* __restrict__ gsum, const float* __restrict__ gsq,
                          const float* __restrict__ gamma, const float* __restrict__ beta,
                          const float* __restrict__ alpha, float* __restrict__ mul, float* __restrict__ add){
  int i = threadIdx.x;            // 1024 = 8*128
  int c = i & 127;
  const float invn = 1.0f / (float)NPG_;
  float m = gsum[i] * invn;
  float a = alpha[c];
  float var = gsq[i] * invn - 2.f * a * m * m + a * a * m * m;
  float mu = gamma[c] * rsqrtf(var + 1e-5f);
  mul[i] = mu;
  add[i] = beta[c] - mu * a * m;
}

// ---------------- fused: normalize h1 (in regs) + sort keys + project to h2p ----------------
__global__ __launch_bounds__(256, 4)
void normproj(const float* __restrict__ h1,
              const float* __restrict__ mul, const float* __restrict__ add,
              const float* __restrict__ rsq_out, const float* __restrict__ W2,
              unsigned long long* __restrict__ keys, float* __restrict__ h2p){
  __shared__ float w2s[128 * 32];  // 16 KB
  int t = threadIdx.x;
  for (int i = t; i < 128 * 32; i += 256) w2s[i] = W2[i];
  __syncthreads();

  int g     = blockIdx.x & 7;
  int wslot = (blockIdx.x >> 3) * 4 + (t >> 6);
  int lane  = t & 63;
  int c     = lane & 31, hh = lane >> 5;
  int wbase = hh * 64 * 32 + c;

  float m0 = mul[g * 128 + lane],      aa0 = add[g * 128 + lane];
  float m1 = mul[g * 128 + 64 + lane], aa1 = add[g * 128 + 64 + lane];

  int nv = (NPG_ - wslot + WSTRIDE_ - 1) / WSTRIDE_;

  int v0 = g * NPG_ + wslot;
  float x0 = __builtin_nontemporal_load(&h1[(size_t)v0 * 128 + lane]);
  float x1 = __builtin_nontemporal_load(&h1[(size_t)v0 * 128 + 64 + lane]);

  for (int i = 0; i < nv; ++i){
    int v = g * NPG_ + wslot + i * WSTRIDE_;
    float cur0 = x0, cur1 = x1;
    if (i + 1 < nv){
      int vn = v + WSTRIDE_;
      x0 = __builtin_nontemporal_load(&h1[(size_t)vn * 128 + lane]);
      x1 = __builtin_nontemporal_load(&h1[(size_t)vn * 128 + 64 + lane]);
    }
    float y0 = lrelu(fmaf(m0, cur0, aa0));
    float y1 = lrelu(fmaf(m1, cur1, aa1));
    float mx = fmaxf(y0, y1);
    for (int o = 1; o < 64; o <<= 1) mx = fmaxf(mx, __shfl_xor(mx, o));
    if (lane == 0){
      unsigned u = __float_as_uint(mx);
      u ^= (u >> 31) ? 0xFFFFFFFFu : 0x80000000u;
      int nloc = v - g * NPG_;
      keys[(size_t)g * NKEY_ + nloc] = ((unsigned long long)(~u) << 32) | (unsigned)nloc;
    }
    float acc = 0.f;
    #pragma unroll
    for (int kk = 0; kk < 64; ++kk){
      float sa = rlanef(y0, kk);
      float sb = rlanef(y1, kk);
      float vk = hh ? sb : sa;
      acc = fmaf(vk, w2s[wbase + kk * 32], acc);
    }
    acc += __shfl_xor(acc, 32);
    if (hh == 0) h2p[(size_t)v * 32 + c] = acc * rsq_out[v];   // cached: spmm2 gathers this
  }
}

// ---------------- top-k selection (2-stage bitonic) ----------------
__global__ void topk_s1(const unsigned long long* __restrict__ keys, unsigned long long* __restrict__ cand){
  __shared__ unsigned long long s[2048];
  int b = blockIdx.x >> 3, ch = blockIdx.x & 7;
  int t = threadIdx.x;            // 256
  for (int i = t; i < 2048; i += 256) s[i] = keys[(size_t)b * NKEY_ + (size_t)ch * 2048 + i];
  for (int k2 = 2; k2 <= 2048; k2 <<= 1){
    for (int j = k2 >> 1; j > 0; j >>= 1){
      __syncthreads();
      for (int i = t; i < 2048; i += 256){
        int p = i ^ j;
        if (p > i){
          unsigned long long A = s[i], C = s[p];
          bool up = ((i & k2) == 0);
          if ((A > C) == up){ s[i] = C; s[p] = A; }
        }
      }
    }
  }
  __syncthreads();
  if (t < 64) cand[(size_t)b * 512 + (size_t)ch * 64 + t] = s[t];
}

__global__ void topk_s2(const unsigned long long* __restrict__ cand, int* __restrict__ topidx){
  __shared__ unsigned long long s[512];
  int b = blockIdx.x;
  int t = threadIdx.x;            // 256
  for (int i = t; i < 512; i += 256) s[i] = cand[(size_t)b * 512 + i];
  for (int k2 = 2; k2 <= 512; k2 <<= 1){
    for (int j = k2 >> 1; j > 0; j >>= 1){
      __syncthreads();
      for (int i = t; i < 512; i += 256){
        int p = i ^ j;
        if (p > i){
          unsigned long long A = s[i], C = s[p];
          bool up = ((i & k2) == 0);
          if ((A > C) == up){ s[i] = C; s[p] = A; }
        }
      }
    }
  }
  __syncthreads();
  if (t < 64) topidx[b * 64 + t] = (int)(s[t] & 0xFFFFFFFFull);
}

// normalize selected raw h1 rows on the fly, sort 128 ascending, final leaky, write
__global__ void emit1(const float* __restrict__ h1, const int* __restrict__ topidx,
                      const float* __restrict__ mul, const float* __restrict__ add,
                      float* __restrict__ out){
  __shared__ float s[128];
  int b = blockIdx.x >> 6, k = blockIdx.x & 63;
  int t = threadIdx.x;            // 128
  int nloc = topidx[b * 64 + k];
  float raw = h1[((size_t)b * NPG_ + nloc) * 128 + t];
  s[t] = lrelu(fmaf(mul[b * 128 + t], raw, add[b * 128 + t]));
  for (int k2 = 2; k2 <= 128; k2 <<= 1){
    for (int j = k2 >> 1; j > 0; j >>= 1){
      __syncthreads();
      int p = t ^ j;
      if (p > t){
        float A = s[t], C = s[p];
        bool up = ((t & k2) == 0);
        if ((A > C) == up){ s[t] = C; s[p] = A; }
      }
    }
  }
  __syncthreads();
  out[(size_t)b * OUT_ROW + (size_t)k * 128 + t] = lrelu(s[t]);
}

// ---------------- layer 2: SpMM on projected h2p (32-d rows) + stats ----------------
__global__ __launch_bounds__(256, 4)
void spmm2_fused(const int* __restrict__ off, const int* __restrict__ cnt,
                 const int* __restrict__ csr_src, const float* __restrict__ csr_w,
                 const float* __restrict__ rsq_in, const float* __restrict__ h2p,
                 float* __restrict__ h2c,
                 float* __restrict__ gsum, float* __restrict__ gsq){
  __shared__ float sred[2][256];
  int t     = threadIdx.x;
  int g     = blockIdx.x & 7;
  int wslot = (blockIdx.x >> 3) * 4 + (t >> 6);
  int lane  = t & 63;
  int c     = lane & 31, hh = lane >> 5;

  int pof = 0, pcn = 0;
  {
    int nl = wslot + lane * WSTRIDE_;
    if (lane < 32 && nl < NPG_){
      int v = g * NPG_ + nl;
      pof = off[v];
      pcn = cnt[v];
    }
  }
  int nv = (NPG_ - wslot + WSTRIDE_ - 1) / WSTRIDE_;

  float ssum = 0.f, ssq = 0.f;

  int ms = 0, msn = 0; float mw = 0.f, mwn = 0.f;
  {
    int sb = rlanei(pof, 0);
    int n  = rlanei(pcn, 0);
    int b  = n < 64 ? n : 64;
    if (lane < b){ ms = __builtin_nontemporal_load(csr_src + sb + lane);
                   mw = __builtin_nontemporal_load(csr_w  + sb + lane); }
  }

  for (int i = 0; i < nv; ++i){
    int sbase = rlanei(pof, i);
    int n     = rlanei(pcn, i);
    int batch = n < 64 ? n : 64;
    if (i + 1 < nv){
      int sb = rlanei(pof, i + 1);
      int n1 = rlanei(pcn, i + 1);
      int b1 = n1 < 64 ? n1 : 64;
      msn = 0; mwn = 0.f;
      if (lane < b1){ msn = __builtin_nontemporal_load(csr_src + sb + lane);
                      mwn = __builtin_nontemporal_load(csr_w  + sb + lane); }
    }

    float acc = 0.f;
    int j = 0;
    #pragma unroll 1
    for (; j + 8 <= batch; j += 8){
      int   sa0 = rlanei(ms, j+0), sb0 = rlanei(ms, j+1);
      int   sa1 = rlanei(ms, j+2), sb1 = rlanei(ms, j+3);
      int   sa2 = rlanei(ms, j+4), sb2 = rlanei(ms, j+5);
      int   sa3 = rlanei(ms, j+6), sb3 = rlanei(ms, j+7);
      float wa0 = rlanef(mw, j+0), wb0 = rlanef(mw, j+1);
      float wa1 = rlanef(mw, j+2), wb1 = rlanef(mw, j+3);
      float wa2 = rlanef(mw, j+4), wb2 = rlanef(mw, j+5);
      float wa3 = rlanef(mw, j+6), wb3 = rlanef(mw, j+7);
      int   s0 = hh ? sb0 : sa0;  float g0 = hh ? wb0 : wa0;
      int   s1 = hh ? sb1 : sa1;  float g1 = hh ? wb1 : wa1;
      int   s2 = hh ? sb2 : sa2;  float g2 = hh ? wb2 : wa2;
      int   s3 = hh ? sb3 : sa3;  float g3 = hh ? wb3 : wa3;
      float f0 = h2p[(size_t)s0 * 32 + c];
      float f1 = h2p[(size_t)s1 * 32 + c];
      float f2 = h2p[(size_t)s2 * 32 + c];
      float f3 = h2p[(size_t)s3 * 32 + c];
      acc = fmaf(g0, f0, acc); acc = fmaf(g1, f1, acc);
      acc = fmaf(g2, f2, acc); acc = fmaf(g3, f3, acc);
    }
    #pragma unroll 1
    for (; j < batch; j += 2){
      int jb = j + 1; if (jb > 63) jb = 63;
      int   sA = rlanei(ms, j);  float wA = rlanef(mw, j);
      int   sB = rlanei(ms, jb); float wB = rlanef(mw, jb);
      int   s  = hh ? sB : sA;
      float wg = hh ? wB : wA;
      acc = fmaf(wg, h2p[(size_t)s * 32 + c], acc);
    }
    acc += __shfl_xor(acc, 32);
    if (n > 64){
      for (int e = 64; e < n; ++e){
        int s = csr_src[sbase + e];
        float wv = csr_w[sbase + e];
        acc = fmaf(wv, h2p[(size_t)s * 32 + c], acc);
      }
    }
    int v = g * NPG_ + wslot + i * WSTRIDE_;
    float val = acc * rsq_in[v];
    if (hh == 0){
      __builtin_nontemporal_store(val, &h2c[(size_t)v * 32 + c]);
      ssum += val; ssq = fmaf(val, val, ssq);
    }
    ms = msn; mw = mwn;
  }

  __syncthreads();
  sred[0][t] = ssum; sred[1][t] = ssq;
  __syncthreads();
  if (t < 32){
    float S = 0.f, Q = 0.f;
    #pragma unroll
    for (int w = 0; w < 4; ++w){
      S += sred[0][t + 64*w] + sred[0][t + 32 + 64*w];
      Q += sred[1][t + 64*w] + sred[1][t + 32 + 64*w];
    }
    atomicAdd(&gsum[g * 32 + t], S);
    atomicAdd(&gsq [g * 32 + t], Q);
  }
}

__global__ void finalize2(const float* __restrict__ gsum, const float* __restrict__ gsq,
                          const float* __restrict__ gamma, const float* __restrict__ beta,
                          const float* __restrict__ alpha, float* __restrict__ mul, float* __restrict__ add){
  int i = threadIdx.x;            // 256 = 8*32
  int c = i & 31;
  const float invn = 1.0f / (float)NPG_;
  float m = gsum[i] * invn;
  float a = alpha[c];
  float var = gsq[i] * invn - 2.f * a * m * m + a * a * m * m;
  float mu = gamma[c] * rsqrtf(var + 1e-5f);
  mul[i] = mu;
  add[i] = beta[c] - mu * a * m;
}

__global__ void norm2(float* __restrict__ h, const float* __restrict__ mul, const float* __restrict__ add,
                      unsigned long long* __restrict__ keys){
  int tid  = blockIdx.x * 256 + threadIdx.x;
  int node = tid >> 5;
  int sl   = tid & 31;
  if (node >= TOTAL_N_) return;
  int b = node / NPG_;
  int nloc = node - b * NPG_;
  float v = h[(size_t)node * 32 + sl];
  v = lrelu(fmaf(mul[b * 32 + sl], v, add[b * 32 + sl]));
  h[(size_t)node * 32 + sl] = v;
  float m = v;
  for (int o = 1; o < 32; o <<= 1) m = fmaxf(m, __shfl_xor(m, o));
  if (sl == 0){
    unsigned u = __float_as_uint(m);
    u ^= (u >> 31) ? 0xFFFFFFFFu : 0x80000000u;
    keys[(size_t)b * NKEY_ + nloc] = ((unsigned long long)(~u) << 32) | (unsigned)nloc;
  }
}

__global__ void emit2(const float* __restrict__ h2, const int* __restrict__ topidx, float* __restrict__ out){
  int b = blockIdx.x >> 6, k = blockIdx.x & 63;
  int lane = threadIdx.x;         // 32
  int nloc = topidx[b * 64 + k];
  float v = h2[((size_t)b * NPG_ + nloc) * 32 + lane];
  for (int k2 = 2; k2 <= 32; k2 <<= 1){
    for (int j = k2 >> 1; j > 0; j >>= 1){
      float o = __shfl_xor(v, j);
      bool up    = ((lane & k2) == 0);
      bool lower = ((lane & j) == 0);
      v = (up == lower) ? fminf(v, o) : fmaxf(v, o);
    }
  }
  out[(size_t)b * OUT_ROW + 8192 + (size_t)k * 32 + lane] = lrelu(v);
}

__global__ void sentinel_kernel(float* out){
  int i = blockIdx.x * 256 + threadIdx.x;
  if (i < B_ * OUT_ROW) out[i] = -777.0f;
}

extern "C" void kernel_launch(void* const* d_in, const int* in_sizes, int n_in,
                              void* d_out, int out_size, void* d_ws, size_t ws_size,
                              hipStream_t stream){
  const float* feat   = (const float*)d_in[0];
  const float* ew     = (const float*)d_in[1];
  const float* W1     = (const float*)d_in[2];
  const float* W2     = (const float*)d_in[3];
  const float* gamma1 = (const float*)d_in[4];
  const float* beta1  = (const float*)d_in[5];
  const float* alpha1 = (const float*)d_in[6];
  const float* gamma2 = (const float*)d_in[7];
  const float* beta2  = (const float*)d_in[8];
  const float* alpha2 = (const float*)d_in[9];
  const int*   esrc   = (const int*)d_in[10];
  const int*   edst   = (const int*)d_in[11];
  float* out = (float*)d_out;

  char* ws = (char*)d_ws;
  auto alloc = [&](size_t bytes) -> char* {
    char* p = ws;
    ws += (bytes + 255) & ~(size_t)255;
    return p;
  };

  // zeroed region (must stay first & contiguous)
  int*   in_cnt  = (int*)  alloc((size_t)TOTAL_N_ * 4);
  int*   out_cnt = (int*)  alloc((size_t)TOTAL_N_ * 4);
  int*   cursor  = (int*)  alloc((size_t)TOTAL_N_ * 4);
  float* gsum1   = (float*)alloc(1024 * 4);
  float* gsq1    = (float*)alloc(1024 * 4);
  float* gsum2   = (float*)alloc(256 * 4);
  float* gsq2    = (float*)alloc(256 * 4);
  size_t zero_bytes = (size_t)(ws - (char*)d_ws);

  float* rsq_in  = (float*)alloc((size_t)TOTAL_N_ * 4);
  float* rsq_out = (float*)alloc((size_t)TOTAL_N_ * 4);
  int*   off     = (int*)  alloc((size_t)TOTAL_N_ * 4);
  int*   bsum    = (int*)  alloc(512 * 4);
  float* mul1    = (float*)alloc(1024 * 4);
  float* add1    = (float*)alloc(1024 * 4);
  float* mul2    = (float*)alloc(256 * 4);
  float* add2    = (float*)alloc(256 * 4);
  int*   topidx1 = (int*)  alloc(512 * 4);
  int*   topidx2 = (int*)  alloc(512 * 4);
  unsigned long long* cand = (unsigned long long*)alloc((size_t)B_ * 512 * 8);
  unsigned long long* keys = (unsigned long long*)alloc((size_t)B_ * NKEY_ * 8);
  int*   csr_src = (int*)  alloc((size_t)TOTAL_E_ * 4);
  float* csr_w   = (float*)alloc((size_t)TOTAL_E_ * 4);
  float* csr_wr  = (float*)alloc((size_t)TOTAL_E_ * 4);
  float* h2p     = (float*)alloc((size_t)TOTAL_N_ * 32 * 4);
  float* h2c     = (float*)alloc((size_t)TOTAL_N_ * 32 * 4);
  float* h1      = (float*)alloc((size_t)TOTAL_N_ * 128 * 4);

  size_t need = (size_t)(ws - (char*)d_ws);
  if (need > ws_size){
    sentinel_kernel<<<(B_ * OUT_ROW + 255) / 256, 256, 0, stream>>>(out);
    return;
  }

  hipMemsetAsync(d_ws, 0, zero_bytes, stream);
  hipMemsetAsync(keys, 0xFF, (size_t)B_ * NKEY_ * 8, stream);

  deg_kernel <<<(TOTAL_E_ + 255) / 256, 256, 0, stream>>>(esrc, edst, out_cnt, in_cnt);
  rsq_kernel <<<NB_SCAN, 256, 0, stream>>>(in_cnt, out_cnt, rsq_in, rsq_out);
  scan_blocks<<<NB_SCAN, 256, 0, stream>>>(in_cnt, off, bsum);
  scan_sums  <<<1, 512, 0, stream>>>(bsum, NB_SCAN);
  scan_add   <<<NB_SCAN, 256, 0, stream>>>(off, bsum);
  fill_csr   <<<(TOTAL_E_ + 255) / 256, 256, 0, stream>>>(esrc, edst, ew, rsq_out, off, cursor,
                                                          csr_src, csr_w, csr_wr);

  // layer 1
  spmm1_fused<<<NBLK_, 256, 0, stream>>>(off, in_cnt, csr_src, csr_wr, feat, W1, rsq_in, h1,
                                         gsum1, gsq1);
  finalize1  <<<1, 1024, 0, stream>>>(gsum1, gsq1, gamma1, beta1, alpha1, mul1, add1);
  normproj   <<<NBLK_, 256, 0, stream>>>(h1, mul1, add1, rsq_out, W2, keys, h2p);
  topk_s1    <<<B_ * 8, 256, 0, stream>>>(keys, cand);
  topk_s2    <<<B_, 256, 0, stream>>>(cand, topidx1);
  emit1      <<<B_ * 64, 128, 0, stream>>>(h1, topidx1, mul1, add1, out);

  // layer 2
  spmm2_fused<<<NBLK_, 256, 0, stream>>>(off, in_cnt, csr_src, csr_w, rsq_in, h2p, h2c,
                                         gsum2, gsq2);
  finalize2  <<<1, 256, 0, stream>>>(gsum2, gsq2, gamma2, beta2, alpha2, mul2, add2);
  norm2      <<<TOTAL_N_ * 32 / 256, 256, 0, stream>>>(h2c, mul2, add2, keys);
  topk_s1    <<<B_ * 8, 256, 0, stream>>>(keys, cand);
  topk_s2    <<<B_, 256, 0, stream>>>(cand, topidx2);
  emit2      <<<B_ * 64, 32, 0, stream>>>(h2c, topidx2, out);
}